// Round 8
// baseline (554.864 us; speedup 1.0000x reference)
//
#include <hip/hip_runtime.h>
#include <hip/hip_cooperative_groups.h>

namespace cg = cooperative_groups;

#define BATCH 8
#define HDIM  512
#define WDIM  512
#define PLANE (HDIM * WDIM)
#define COOP_BLOCKS 2048

typedef _Float16 half2v __attribute__((ext_vector_type(2)));
typedef _Float16 half8v __attribute__((ext_vector_type(8)));

// two adjacent texels (x0,x0+1), each (c0,c1),(c2,0) as half2 pairs; 16B
struct __align__(8) HQuad { half2v p0, p1, p2, p3; };

#if __has_builtin(__builtin_amdgcn_fdot2)
#define FDOT2(a, b, c) __builtin_amdgcn_fdot2((a), (b), (c), false)
#else
#define FDOT2(a, b, c) fmaf((float)(a).x, (float)(b).x, fmaf((float)(a).y, (float)(b).y, (c)))
#endif

// ---------- phase 1: pack 4 px/thread, NCHW fp32 -> [B,H,W] half4 ----------
__device__ __forceinline__ void pack_tile(int vblk, int t,
    const float* __restrict__ x, char* __restrict__ xpack)
{
    int b = vblk & 7;                           // image -> XCD locality
    int u = ((vblk >> 3) << 8) + t;             // [0, PLANE/4)
    const float* xb = x + (size_t)b * 3 * PLANE;
    int pix = u << 2;
    float4 a0 = *(const float4*)(xb + pix);
    float4 a1 = *(const float4*)(xb + PLANE + pix);
    float4 a2 = *(const float4*)(xb + 2 * PLANE + pix);
    half8v o0, o1;
    o0[0] = (_Float16)a0.x; o0[1] = (_Float16)a1.x; o0[2] = (_Float16)a2.x; o0[3] = (_Float16)0.f;
    o0[4] = (_Float16)a0.y; o0[5] = (_Float16)a1.y; o0[6] = (_Float16)a2.y; o0[7] = (_Float16)0.f;
    o1[0] = (_Float16)a0.z; o1[1] = (_Float16)a1.z; o1[2] = (_Float16)a2.z; o1[3] = (_Float16)0.f;
    o1[4] = (_Float16)a0.w; o1[5] = (_Float16)a1.w; o1[6] = (_Float16)a2.w; o1[7] = (_Float16)0.f;
    half8v* xp = (half8v*)xpack;
    size_t base = (size_t)b * (PLANE / 2) + (size_t)u * 2;
    xp[base]     = o0;
    xp[base + 1] = o1;
}

// ---------- phase 2: one 256-px half-row tile (v7 logic) ----------
__device__ __forceinline__ void main_tile(int vt, int t,
    const float* __restrict__ x, const char* __restrict__ xpack,
    const float* __restrict__ w1, const float* __restrict__ b1,
    const float* __restrict__ w2, const float* __restrict__ b2,
    float* __restrict__ out)
{
    int b    = vt & 7;                   // image -> XCD locality
    int rest = vt >> 3;                  // [0, 1024)
    int i    = rest >> 1;                // SCALAR row
    int j    = ((rest & 1) << 8) + t;    // 0..511

    const float* xb = x + (size_t)b * 3 * PLANE;
    const char*  hb = xpack + ((size_t)b << 21);   // PLANE * 8 bytes

    // ---- 3x3 conv (pad=1); scalar row-base addressing ----
    float acc[8];
#pragma unroll
    for (int e = 0; e < 8; e++) acc[e] = b1[e];

    int cm1 = j - 1; if (cm1 < 0) cm1 = 0;
    int cp1 = j + 1; if (cp1 > 511) cp1 = 511;
    bool jlo = (j == 0), jhi = (j == 511);

    if (i >= 1 && i <= 510) {            // interior rows (uniform branch)
#pragma unroll
        for (int di = 0; di < 3; di++) {
            const float* row = xb + ((i + di - 1) << 9);
#pragma unroll
            for (int c = 0; c < 3; c++) {
                const float* rc = row + c * PLANE;
                float vm = rc[cm1]; if (jlo) vm = 0.f;
                float v0 = rc[j];
                float vp = rc[cp1]; if (jhi) vp = 0.f;
#pragma unroll
                for (int e = 0; e < 8; e++) {
                    const float* we = &w1[e * 27 + c * 9 + di * 3];
                    acc[e] = fmaf(vm, we[0], acc[e]);
                    acc[e] = fmaf(v0, we[1], acc[e]);
                    acc[e] = fmaf(vp, we[2], acc[e]);
                }
            }
        }
    } else {                              // y-edge rows (16/8192 tiles)
#pragma unroll
        for (int di = 0; di < 3; di++) {
            int y = i + di - 1;
            bool yv = (unsigned)y < (unsigned)HDIM;
            const float* row = xb + ((yv ? y : 0) << 9);
#pragma unroll
            for (int c = 0; c < 3; c++) {
                const float* rc = row + c * PLANE;
                float vm = rc[cm1]; if (jlo || !yv) vm = 0.f;
                float v0 = rc[j];   if (!yv)        v0 = 0.f;
                float vp = rc[cp1]; if (jhi || !yv) vp = 0.f;
#pragma unroll
                for (int e = 0; e < 8; e++) {
                    const float* we = &w1[e * 27 + c * 9 + di * 3];
                    acc[e] = fmaf(vm, we[0], acc[e]);
                    acc[e] = fmaf(v0, we[1], acc[e]);
                    acc[e] = fmaf(vp, we[2], acc[e]);
                }
            }
        }
    }

    // ---- sigmoid, pre-scaled by 256 ----
    float s256[8];
#pragma unroll
    for (int e = 0; e < 8; e++)
        s256[e] = 256.0f * __builtin_amdgcn_rcpf(1.0f + __expf(-acc[e]));

    // ---- w2 rows packed to half2 (wave-uniform) ----
    half2v w2a[5], w2b[5];
#pragma unroll
    for (int q = 0; q < 5; q++) {
        w2a[q][0] = (_Float16)w2[q * 3];
        w2a[q][1] = (_Float16)w2[q * 3 + 1];
        w2b[q][0] = (_Float16)w2[q * 3 + 2];
        w2b[q][1] = (_Float16)0.f;
    }

    const float k511 = 256.0f / 511.0f;
    float fxb = fmaf((float)i, k511, 255.5f);   // feeds gx (reference axis swap)
    float fyb = fmaf((float)j, k511, 255.5f);

    // ---- gather phase 1: addresses + weights for 5 points ----
    int   adr[5][2];
    float wY0[5], wY1[5], wX0[5], wX1[5];
#pragma unroll
    for (int q = 0; q < 5; q++) {
        float ixf = (q < 4) ? (fxb + s256[2 * q])     : fxb;
        float iyf = (q < 4) ? (fyb + s256[2 * q + 1]) : fyb;
        float wx1 = ixf - truncf(ixf);
        float wy1 = iyf - truncf(iyf);
        int ix0 = (int)ixf, iy0 = (int)iyf;     // positive: trunc == floor
        float wx0 = 1.f - wx1, wy0 = 1.f - wy1;

        float wx0v = (ix0 <= 511) ? wx0 : 0.f;
        float wx1v = (ix0 <= 510) ? wx1 : 0.f;
        float wy0v = (iy0 <= 511) ? wy0 : 0.f;
        float wy1v = (iy0 <= 510) ? wy1 : 0.f;
        int x0c = min(ix0, 511);
        int y0c = min(iy0, 511), y1c = min(iy0 + 1, 511);

        float wxs = wx0v + wx1v;
        wX0[q] = wx0v; wX1[q] = wx1v;
        wY0[q] = wy0v; wY1[q] = wy1v;
        adr[q][0] = (wy0v * wxs > 0.f) ? ((y0c << 9) + x0c) : 0;
        adr[q][1] = (wy1v * wxs > 0.f) ? ((y1c << 9) + x0c) : 0;
    }

    // ---- gather phase 2: all 10 pair-loads back-to-back ----
    HQuad qv[5][2];
#pragma unroll
    for (int q = 0; q < 5; q++) {
        qv[q][0] = *(const HQuad*)(hb + ((size_t)adr[q][0] << 3));
        qv[q][1] = *(const HQuad*)(hb + ((size_t)adr[q][1] << 3));
    }

    // ---- gather phase 3: fp16 dot per texel, bilinear combine ----
    float og[3] = {0.f, 0.f, 0.f};
#pragma unroll
    for (int q = 0; q < 5; q++) {
        int g = q / 3;              // 0,0,0,1,1
        float dl0 = FDOT2(qv[q][0].p0, w2a[q], FDOT2(qv[q][0].p1, w2b[q], 0.f));
        float dh0 = FDOT2(qv[q][0].p2, w2a[q], FDOT2(qv[q][0].p3, w2b[q], 0.f));
        float dl1 = FDOT2(qv[q][1].p0, w2a[q], FDOT2(qv[q][1].p1, w2b[q], 0.f));
        float dh1 = FDOT2(qv[q][1].p2, w2a[q], FDOT2(qv[q][1].p3, w2b[q], 0.f));
        float r0 = fmaf(dh0, wX1[q], dl0 * wX0[q]);
        float r1 = fmaf(dh1, wX1[q], dl1 * wX0[q]);
        og[g] = fmaf(r1, wY1[q], fmaf(r0, wY0[q], og[g]));
    }

    // ---- mirror points p=5..8: only pixel (0,0) of each image contributes ----
    if ((i | j) == 0) {
#pragma unroll
        for (int p = 5; p < 9; p++) {
            float ixf = fxb + 512.0f - s256[2 * (p - 5)];
            float iyf = fyb + 512.0f - s256[2 * (p - 5) + 1];
            float ix0f = floorf(ixf), iy0f = floorf(iyf);
            float wx1 = ixf - ix0f, wy1 = iyf - iy0f;
            float wx0 = 1.f - wx1,  wy0 = 1.f - wy1;
            int ix0 = (int)ix0f, iy0 = (int)iy0f;
            float s0 = 0.f, s1 = 0.f, s2 = 0.f;
            for (int cy = 0; cy < 2; cy++) {
                int yc2 = iy0 + cy;
                if (yc2 < 0 || yc2 >= HDIM) continue;
                float wy = cy ? wy1 : wy0;
                for (int cx = 0; cx < 2; cx++) {
                    int xcc2 = ix0 + cx;
                    if (xcc2 < 0 || xcc2 >= WDIM) continue;
                    float wgt = wy * (cx ? wx1 : wx0);
                    int base = (yc2 << 9) + xcc2;
                    s0 = fmaf(xb[base],             wgt, s0);
                    s1 = fmaf(xb[PLANE + base],     wgt, s1);
                    s2 = fmaf(xb[2 * PLANE + base], wgt, s2);
                }
            }
            int g  = p / 3;
            int k0 = (p % 3) * 3;
            og[g] = fmaf(s0, w2[g * 9 + k0 + 0], og[g]);
            og[g] = fmaf(s1, w2[g * 9 + k0 + 1], og[g]);
            og[g] = fmaf(s2, w2[g * 9 + k0 + 2], og[g]);
        }
    }

    // ---- bias + relu + store ----
    size_t ob = (size_t)(b * 3) * PLANE + ((size_t)i << 9) + j;
#pragma unroll
    for (int g = 0; g < 3; g++) {
        float v = og[g] + b2[g];
        out[ob + (size_t)g * PLANE] = v > 0.f ? v : 0.f;
    }
}

// ---------- fused cooperative kernel: pack -> grid.sync -> 4 main tiles ----------
__global__ __launch_bounds__(256, 8) void seesaw_coop(
    const float* __restrict__ x, char* __restrict__ xpack,
    const float* __restrict__ w1, const float* __restrict__ b1,
    const float* __restrict__ w2, const float* __restrict__ b2,
    float* __restrict__ out)
{
    pack_tile(blockIdx.x, threadIdx.x, x, xpack);
    __threadfence();
    cg::this_grid().sync();
#pragma unroll
    for (int r = 0; r < 4; r++)
        main_tile(blockIdx.x + COOP_BLOCKS * r, threadIdx.x,
                  x, xpack, w1, b1, w2, b2, out);
}

// ---------- standalone fallbacks (round-7 path) ----------
__global__ __launch_bounds__(256) void repack_h4x(
    const float* __restrict__ x, char* __restrict__ xpack)
{
    pack_tile(blockIdx.x, threadIdx.x, x, xpack);
}

__global__ __launch_bounds__(256) void seesaw_v7(
    const float* __restrict__ x, const char* __restrict__ xpack,
    const float* __restrict__ w1, const float* __restrict__ b1,
    const float* __restrict__ w2, const float* __restrict__ b2,
    float* __restrict__ out)
{
    main_tile(blockIdx.x, threadIdx.x, x, xpack, w1, b1, w2, b2, out);
}

// ---------- no-workspace fallback (round-1 style) ----------
__global__ __launch_bounds__(256) void seesaw_fused_v1(
    const float* __restrict__ x, const float* __restrict__ w1,
    const float* __restrict__ b1, const float* __restrict__ w2,
    const float* __restrict__ b2, float* __restrict__ out)
{
    int t = threadIdx.x;
    int gid = blockIdx.x * 256 + t;
    int j = gid & (WDIM - 1);
    int i = (gid >> 9) & (HDIM - 1);
    int b = gid >> 18;
    const float* xb = x + (size_t)b * 3 * PLANE;
    float acc[8];
#pragma unroll
    for (int e = 0; e < 8; e++) acc[e] = b1[e];
#pragma unroll
    for (int di = 0; di < 3; di++) {
        int y = i + di - 1;
        if (y < 0 || y >= HDIM) continue;
#pragma unroll
        for (int dj = 0; dj < 3; dj++) {
            int xc = j + dj - 1;
            if (xc < 0 || xc >= WDIM) continue;
            size_t base = (size_t)y * WDIM + xc;
#pragma unroll
            for (int c = 0; c < 3; c++) {
                float v = xb[(size_t)c * PLANE + base];
#pragma unroll
                for (int e = 0; e < 8; e++)
                    acc[e] = fmaf(v, w1[e * 27 + c * 9 + di * 3 + dj], acc[e]);
            }
        }
    }
    float s[8];
#pragma unroll
    for (int e = 0; e < 8; e++) s[e] = 1.0f / (1.0f + __expf(-acc[e]));
    const float inv511 = 1.0f / 511.0f;
    float bx = (float)i * inv511, by = (float)j * inv511;
    float og0 = 0.f, og1 = 0.f, og2 = 0.f;
#pragma unroll
    for (int p = 0; p < 9; p++) {
        float c0, c1;
        if (p < 4)       { c0 = s[2 * p];              c1 = s[2 * p + 1]; }
        else if (p == 4) { c0 = 0.f;                   c1 = 0.f; }
        else             { c0 = 2.0f - s[2 * (p - 5)]; c1 = 2.0f - s[2 * (p - 5) + 1]; }
        float ixf = (bx + c0) * 256.0f + 255.5f;
        float iyf = (by + c1) * 256.0f + 255.5f;
        float ix0f = floorf(ixf), iy0f = floorf(iyf);
        float wx1 = ixf - ix0f, wy1 = iyf - iy0f;
        float wx0 = 1.f - wx1,  wy0 = 1.f - wy1;
        int ix0 = (int)ix0f, iy0 = (int)iy0f;
        float s0 = 0.f, s1 = 0.f, s2 = 0.f;
#pragma unroll
        for (int cy = 0; cy < 2; cy++) {
            int yc = iy0 + cy;
            if (yc < 0 || yc >= HDIM) continue;
            float wy = cy ? wy1 : wy0;
#pragma unroll
            for (int cx = 0; cx < 2; cx++) {
                int xcc = ix0 + cx;
                if (xcc < 0 || xcc >= WDIM) continue;
                float wgt = wy * (cx ? wx1 : wx0);
                size_t base = (size_t)yc * WDIM + xcc;
                s0 = fmaf(xb[base],             wgt, s0);
                s1 = fmaf(xb[PLANE + base],     wgt, s1);
                s2 = fmaf(xb[2 * PLANE + base], wgt, s2);
            }
        }
        int g  = p / 3;
        int k0 = (p % 3) * 3;
        float* og = (g == 0) ? &og0 : (g == 1) ? &og1 : &og2;
        *og = fmaf(s0, w2[g * 9 + k0 + 0], *og);
        *og = fmaf(s1, w2[g * 9 + k0 + 1], *og);
        *og = fmaf(s2, w2[g * 9 + k0 + 2], *og);
    }
    size_t ob = (size_t)(b * 3) * PLANE + (size_t)i * WDIM + j;
    float v0 = og0 + b2[0], v1 = og1 + b2[1], v2 = og2 + b2[2];
    out[ob]             = v0 > 0.f ? v0 : 0.f;
    out[ob + PLANE]     = v1 > 0.f ? v1 : 0.f;
    out[ob + 2 * PLANE] = v2 > 0.f ? v2 : 0.f;
}

extern "C" void kernel_launch(void* const* d_in, const int* in_sizes, int n_in,
                              void* d_out, int out_size, void* d_ws, size_t ws_size,
                              hipStream_t stream) {
    const float* x  = (const float*)d_in[0];
    const float* w1 = (const float*)d_in[1];
    const float* b1 = (const float*)d_in[2];
    const float* w2 = (const float*)d_in[3];
    const float* b2 = (const float*)d_in[4];
    float* out = (float*)d_out;

    int total = BATCH * HDIM * WDIM;                 // 2,097,152
    size_t need = (size_t)total * 8 + 16;            // 16 MiB fp16x4 pack + pad

    if (ws_size < need) {
        seesaw_fused_v1<<<total / 256, 256, 0, stream>>>(x, w1, b1, w2, b2, out);
        return;
    }

    char* xpack = (char*)d_ws;
    void* args[] = { (void*)&x, (void*)&xpack, (void*)&w1, (void*)&b1,
                     (void*)&w2, (void*)&b2, (void*)&out };
    hipError_t err = hipLaunchCooperativeKernel(
        (const void*)seesaw_coop, dim3(COOP_BLOCKS), dim3(256), args, 0, stream);

    if (err != hipSuccess) {
        // cooperative launch rejected (capture-unsupported / too-large):
        // proven two-kernel round-7 path, identical math.
        repack_h4x<<<COOP_BLOCKS, 256, 0, stream>>>(x, xpack);
        seesaw_v7<<<total / 256, 256, 0, stream>>>(x, xpack, w1, b1, w2, b2, out);
    }
}

// Round 9
// 128.407 us; speedup vs baseline: 4.3211x; 4.3211x over previous
//
#include <hip/hip_runtime.h>

#define BATCH 8
#define HDIM  512
#define WDIM  512
#define PLANE (HDIM * WDIM)

typedef _Float16 half2v __attribute__((ext_vector_type(2)));
typedef _Float16 half8v __attribute__((ext_vector_type(8)));
typedef float    f2v    __attribute__((ext_vector_type(2)));

// two adjacent texels (x0,x0+1), each (c0,c1),(c2,0) as half2 pairs; 16B
struct __align__(8) HQuad { half2v p0, p1, p2, p3; };

#if __has_builtin(__builtin_amdgcn_fdot2)
#define FDOT2(a, b, c) __builtin_amdgcn_fdot2((a), (b), (c), false)
#else
#define FDOT2(a, b, c) fmaf((float)(a).x, (float)(b).x, fmaf((float)(a).y, (float)(b).y, (c)))
#endif

#if __has_builtin(__builtin_amdgcn_exp2f)
#define EXP2F(x) __builtin_amdgcn_exp2f(x)
#else
#define EXP2F(x) exp2f(x)
#endif

// ---------- repack: NCHW fp32 -> [B,H,W] half4; XCD-swizzled (img = blk&7) ----------
__global__ __launch_bounds__(256) void repack_h4x(
    const float* __restrict__ x,   // [B,3,H,W]
    half8v* __restrict__ xp)       // pairs of half4
{
    int b = blockIdx.x & 7;
    int u = ((blockIdx.x >> 3) << 8) + threadIdx.x;   // [0, PLANE/4)
    const float* xb = x + (size_t)b * 3 * PLANE;
    int pix = u << 2;
    float4 a0 = *(const float4*)(xb + pix);
    float4 a1 = *(const float4*)(xb + PLANE + pix);
    float4 a2 = *(const float4*)(xb + 2 * PLANE + pix);
    half8v o0, o1;
    o0[0] = (_Float16)a0.x; o0[1] = (_Float16)a1.x; o0[2] = (_Float16)a2.x; o0[3] = (_Float16)0.f;
    o0[4] = (_Float16)a0.y; o0[5] = (_Float16)a1.y; o0[6] = (_Float16)a2.y; o0[7] = (_Float16)0.f;
    o1[0] = (_Float16)a0.z; o1[1] = (_Float16)a1.z; o1[2] = (_Float16)a2.z; o1[3] = (_Float16)0.f;
    o1[4] = (_Float16)a0.w; o1[5] = (_Float16)a1.w; o1[6] = (_Float16)a2.w; o1[7] = (_Float16)0.f;
    size_t base = (size_t)b * (PLANE / 2) + (size_t)u * 2;
    xp[base]     = o0;
    xp[base + 1] = o1;
}

// ---------- main: 1 px/thread; scalar row bases; pk_fma conv; XCD-swizzled ----------
__global__ __launch_bounds__(256) void seesaw_v8(
    const float* __restrict__ x,     // [B,3,H,W] fp32 (conv + mirror)
    const char* __restrict__ xpack,  // [B,H,W] half4 as bytes
    const float* __restrict__ w1, const float* __restrict__ b1,
    const float* __restrict__ w2, const float* __restrict__ b2,
    float* __restrict__ out)
{
    int t = threadIdx.x;
    int b    = blockIdx.x & 7;           // image -> XCD locality
    int rest = blockIdx.x >> 3;          // [0, 1024)
    int i    = rest >> 1;                // SCALAR row (block covers half a row)
    int j    = ((rest & 1) << 8) + t;    // 0..511

    const float* xb = x + (size_t)b * 3 * PLANE;
    const char*  hb = xpack + ((size_t)b << 21);   // PLANE * 8 bytes

    // ---- gather the 27 conv inputs (flat, masked), scalar row bases ----
    float v[27];   // k = c*9 + di*3 + dj
    int cm1 = j - 1; if (cm1 < 0) cm1 = 0;
    int cp1 = j + 1; if (cp1 > 511) cp1 = 511;
    bool jlo = (j == 0), jhi = (j == 511);

    if (i >= 1 && i <= 510) {            // interior rows (uniform branch)
#pragma unroll
        for (int di = 0; di < 3; di++) {
            const float* row = xb + ((i + di - 1) << 9);
#pragma unroll
            for (int c = 0; c < 3; c++) {
                const float* rc = row + c * PLANE;
                float vm = rc[cm1]; if (jlo) vm = 0.f;
                float v0 = rc[j];
                float vp = rc[cp1]; if (jhi) vp = 0.f;
                v[c * 9 + di * 3 + 0] = vm;
                v[c * 9 + di * 3 + 1] = v0;
                v[c * 9 + di * 3 + 2] = vp;
            }
        }
    } else {                              // y-edge rows (16/8192 blocks)
#pragma unroll
        for (int di = 0; di < 3; di++) {
            int y = i + di - 1;
            bool yv = (unsigned)y < (unsigned)HDIM;
            const float* row = xb + ((yv ? y : 0) << 9);
#pragma unroll
            for (int c = 0; c < 3; c++) {
                const float* rc = row + c * PLANE;
                float vm = rc[cm1]; if (jlo || !yv) vm = 0.f;
                float v0 = rc[j];   if (!yv)        v0 = 0.f;
                float vp = rc[cp1]; if (jhi || !yv) vp = 0.f;
                v[c * 9 + di * 3 + 0] = vm;
                v[c * 9 + di * 3 + 1] = v0;
                v[c * 9 + di * 3 + 2] = vp;
            }
        }
    }

    // ---- 27-tap dot via packed f32 FMA (v_pk_fma_f32) ----
    f2v V[13];
#pragma unroll
    for (int k = 0; k < 13; k++) { V[k][0] = v[2 * k]; V[k][1] = v[2 * k + 1]; }

    float acc[8];
#pragma unroll
    for (int e = 0; e < 8; e++) {
        const float* we = w1 + e * 27;
        f2v a2; a2[0] = b1[e]; a2[1] = 0.f;
#pragma unroll
        for (int k = 0; k < 13; k++) {
            f2v ww; ww[0] = we[2 * k]; ww[1] = we[2 * k + 1];
            a2 = __builtin_elementwise_fma(V[k], ww, a2);
        }
        acc[e] = a2[0] + a2[1] + v[26] * we[26];
    }

    // ---- sigmoid via raw exp2, pre-scaled by 256 ----
    const float NLOG2E = -1.44269504f;
    float s256[8];
#pragma unroll
    for (int e = 0; e < 8; e++)
        s256[e] = 256.0f * __builtin_amdgcn_rcpf(1.0f + EXP2F(acc[e] * NLOG2E));

    // ---- w2 rows packed to half2 (wave-uniform) ----
    half2v w2a[5], w2b[5];
#pragma unroll
    for (int q = 0; q < 5; q++) {
        w2a[q][0] = (_Float16)w2[q * 3];
        w2a[q][1] = (_Float16)w2[q * 3 + 1];
        w2b[q][0] = (_Float16)w2[q * 3 + 2];
        w2b[q][1] = (_Float16)0.f;
    }

    const float k511 = 256.0f / 511.0f;
    float fxb = fmaf((float)i, k511, 255.5f);   // feeds gx (reference axis swap)
    float fyb = fmaf((float)j, k511, 255.5f);

    // ---- gather phase 1: addresses + weights for 5 points ----
    int   adr[5][2];
    float wY0[5], wY1[5], wX0[5], wX1[5];
#pragma unroll
    for (int q = 0; q < 5; q++) {
        float ixf = (q < 4) ? (fxb + s256[2 * q])     : fxb;
        float iyf = (q < 4) ? (fyb + s256[2 * q + 1]) : fyb;
        float wx1 = ixf - truncf(ixf);
        float wy1 = iyf - truncf(iyf);
        int ix0 = (int)ixf, iy0 = (int)iyf;     // positive: trunc == floor
        float wx0 = 1.f - wx1, wy0 = 1.f - wy1;

        float wx0v = (ix0 <= 511) ? wx0 : 0.f;
        float wx1v = (ix0 <= 510) ? wx1 : 0.f;
        float wy0v = (iy0 <= 511) ? wy0 : 0.f;
        float wy1v = (iy0 <= 510) ? wy1 : 0.f;
        int x0c = min(ix0, 511);
        int y0c = min(iy0, 511), y1c = min(iy0 + 1, 511);

        float wxs = wx0v + wx1v;
        wX0[q] = wx0v; wX1[q] = wx1v;
        wY0[q] = wy0v; wY1[q] = wy1v;
        adr[q][0] = (wy0v * wxs > 0.f) ? ((y0c << 9) + x0c) : 0;
        adr[q][1] = (wy1v * wxs > 0.f) ? ((y1c << 9) + x0c) : 0;
    }

    // ---- gather phase 2: all 10 pair-loads back-to-back ----
    HQuad qv[5][2];
#pragma unroll
    for (int q = 0; q < 5; q++) {
        qv[q][0] = *(const HQuad*)(hb + ((size_t)adr[q][0] << 3));
        qv[q][1] = *(const HQuad*)(hb + ((size_t)adr[q][1] << 3));
    }

    // ---- gather phase 3: fp16 dot per texel, bilinear combine ----
    float og[3] = {0.f, 0.f, 0.f};
#pragma unroll
    for (int q = 0; q < 5; q++) {
        int g = q / 3;              // 0,0,0,1,1
        float dl0 = FDOT2(qv[q][0].p0, w2a[q], FDOT2(qv[q][0].p1, w2b[q], 0.f));
        float dh0 = FDOT2(qv[q][0].p2, w2a[q], FDOT2(qv[q][0].p3, w2b[q], 0.f));
        float dl1 = FDOT2(qv[q][1].p0, w2a[q], FDOT2(qv[q][1].p1, w2b[q], 0.f));
        float dh1 = FDOT2(qv[q][1].p2, w2a[q], FDOT2(qv[q][1].p3, w2b[q], 0.f));
        float r0 = fmaf(dh0, wX1[q], dl0 * wX0[q]);
        float r1 = fmaf(dh1, wX1[q], dl1 * wX0[q]);
        og[g] = fmaf(r1, wY1[q], fmaf(r0, wY0[q], og[g]));
    }

    // ---- mirror points p=5..8: only pixel (0,0) of each image contributes ----
    if ((i | j) == 0) {
#pragma unroll
        for (int p = 5; p < 9; p++) {
            float ixf = fxb + 512.0f - s256[2 * (p - 5)];
            float iyf = fyb + 512.0f - s256[2 * (p - 5) + 1];
            float ix0f = floorf(ixf), iy0f = floorf(iyf);
            float wx1 = ixf - ix0f, wy1 = iyf - iy0f;
            float wx0 = 1.f - wx1,  wy0 = 1.f - wy1;
            int ix0 = (int)ix0f, iy0 = (int)iy0f;
            float s0 = 0.f, s1 = 0.f, s2 = 0.f;
            for (int cy = 0; cy < 2; cy++) {
                int yc2 = iy0 + cy;
                if (yc2 < 0 || yc2 >= HDIM) continue;
                float wy = cy ? wy1 : wy0;
                for (int cx = 0; cx < 2; cx++) {
                    int xcc2 = ix0 + cx;
                    if (xcc2 < 0 || xcc2 >= WDIM) continue;
                    float wgt = wy * (cx ? wx1 : wx0);
                    int base = (yc2 << 9) + xcc2;
                    s0 = fmaf(xb[base],             wgt, s0);
                    s1 = fmaf(xb[PLANE + base],     wgt, s1);
                    s2 = fmaf(xb[2 * PLANE + base], wgt, s2);
                }
            }
            int g  = p / 3;
            int k0 = (p % 3) * 3;
            og[g] = fmaf(s0, w2[g * 9 + k0 + 0], og[g]);
            og[g] = fmaf(s1, w2[g * 9 + k0 + 1], og[g]);
            og[g] = fmaf(s2, w2[g * 9 + k0 + 2], og[g]);
        }
    }

    // ---- bias + relu + store ----
    size_t ob = (size_t)(b * 3) * PLANE + ((size_t)i << 9) + j;
#pragma unroll
    for (int g = 0; g < 3; g++) {
        float vv = og[g] + b2[g];
        out[ob + (size_t)g * PLANE] = vv > 0.f ? vv : 0.f;
    }
}

// ---------- no-workspace fallback (round-1 style) ----------
__global__ __launch_bounds__(256) void seesaw_fused_v1(
    const float* __restrict__ x, const float* __restrict__ w1,
    const float* __restrict__ b1, const float* __restrict__ w2,
    const float* __restrict__ b2, float* __restrict__ out)
{
    int t = threadIdx.x;
    int gid = blockIdx.x * 256 + t;
    int j = gid & (WDIM - 1);
    int i = (gid >> 9) & (HDIM - 1);
    int b = gid >> 18;
    const float* xb = x + (size_t)b * 3 * PLANE;
    float acc[8];
#pragma unroll
    for (int e = 0; e < 8; e++) acc[e] = b1[e];
#pragma unroll
    for (int di = 0; di < 3; di++) {
        int y = i + di - 1;
        if (y < 0 || y >= HDIM) continue;
#pragma unroll
        for (int dj = 0; dj < 3; dj++) {
            int xc = j + dj - 1;
            if (xc < 0 || xc >= WDIM) continue;
            size_t base = (size_t)y * WDIM + xc;
#pragma unroll
            for (int c = 0; c < 3; c++) {
                float v = xb[(size_t)c * PLANE + base];
#pragma unroll
                for (int e = 0; e < 8; e++)
                    acc[e] = fmaf(v, w1[e * 27 + c * 9 + di * 3 + dj], acc[e]);
            }
        }
    }
    float s[8];
#pragma unroll
    for (int e = 0; e < 8; e++) s[e] = 1.0f / (1.0f + __expf(-acc[e]));
    const float inv511 = 1.0f / 511.0f;
    float bx = (float)i * inv511, by = (float)j * inv511;
    float og0 = 0.f, og1 = 0.f, og2 = 0.f;
#pragma unroll
    for (int p = 0; p < 9; p++) {
        float c0, c1;
        if (p < 4)       { c0 = s[2 * p];              c1 = s[2 * p + 1]; }
        else if (p == 4) { c0 = 0.f;                   c1 = 0.f; }
        else             { c0 = 2.0f - s[2 * (p - 5)]; c1 = 2.0f - s[2 * (p - 5) + 1]; }
        float ixf = (bx + c0) * 256.0f + 255.5f;
        float iyf = (by + c1) * 256.0f + 255.5f;
        float ix0f = floorf(ixf), iy0f = floorf(iyf);
        float wx1 = ixf - ix0f, wy1 = iyf - iy0f;
        float wx0 = 1.f - wx1,  wy0 = 1.f - wy1;
        int ix0 = (int)ix0f, iy0 = (int)iy0f;
        float s0 = 0.f, s1 = 0.f, s2 = 0.f;
#pragma unroll
        for (int cy = 0; cy < 2; cy++) {
            int yc = iy0 + cy;
            if (yc < 0 || yc >= HDIM) continue;
            float wy = cy ? wy1 : wy0;
#pragma unroll
            for (int cx = 0; cx < 2; cx++) {
                int xcc = ix0 + cx;
                if (xcc < 0 || xcc >= WDIM) continue;
                float wgt = wy * (cx ? wx1 : wx0);
                size_t base = (size_t)yc * WDIM + xcc;
                s0 = fmaf(xb[base],             wgt, s0);
                s1 = fmaf(xb[PLANE + base],     wgt, s1);
                s2 = fmaf(xb[2 * PLANE + base], wgt, s2);
            }
        }
        int g  = p / 3;
        int k0 = (p % 3) * 3;
        float* og = (g == 0) ? &og0 : (g == 1) ? &og1 : &og2;
        *og = fmaf(s0, w2[g * 9 + k0 + 0], *og);
        *og = fmaf(s1, w2[g * 9 + k0 + 1], *og);
        *og = fmaf(s2, w2[g * 9 + k0 + 2], *og);
    }
    size_t ob = (size_t)(b * 3) * PLANE + (size_t)i * WDIM + j;
    float v0 = og0 + b2[0], v1 = og1 + b2[1], v2 = og2 + b2[2];
    out[ob]             = v0 > 0.f ? v0 : 0.f;
    out[ob + PLANE]     = v1 > 0.f ? v1 : 0.f;
    out[ob + 2 * PLANE] = v2 > 0.f ? v2 : 0.f;
}

extern "C" void kernel_launch(void* const* d_in, const int* in_sizes, int n_in,
                              void* d_out, int out_size, void* d_ws, size_t ws_size,
                              hipStream_t stream) {
    const float* x  = (const float*)d_in[0];
    const float* w1 = (const float*)d_in[1];
    const float* b1 = (const float*)d_in[2];
    const float* w2 = (const float*)d_in[3];
    const float* b2 = (const float*)d_in[4];
    float* out = (float*)d_out;

    int total = BATCH * HDIM * WDIM;                 // 2,097,152
    size_t need = (size_t)total * 8 + 16;            // 16 MiB fp16x4 pack + pad

    if (ws_size >= need) {
        repack_h4x<<<total / 4 / 256, 256, 0, stream>>>(x, (half8v*)d_ws);
        seesaw_v8<<<total / 256, 256, 0, stream>>>(x, (const char*)d_ws,
                                                   w1, b1, w2, b2, out);
    } else {
        seesaw_fused_v1<<<total / 256, 256, 0, stream>>>(x, w1, b1, w2, b2, out);
    }
}

// Round 10
// 124.580 us; speedup vs baseline: 4.4539x; 1.0307x over previous
//
#include <hip/hip_runtime.h>

#define BATCH 8
#define HDIM  512
#define WDIM  512
#define PLANE (HDIM * WDIM)

// Only pack rows/cols >= 255 are ever gathered (ix = i*256/511 + 255.5 + 256*sigmoid > 255.5).
// Pack rows 254..511 (= 129 row-pairs) — quadrant repack, 2x fewer bytes, 4x fewer threads.
#define PACK_ROW0   254
#define PACK_PAIRS  129
#define DEAD_ADDR   ((255 << 9) + 255)   // packed texel; weight is 0 whenever used

typedef _Float16 half2v __attribute__((ext_vector_type(2)));
typedef _Float16 half8v __attribute__((ext_vector_type(8)));
typedef float    f2v    __attribute__((ext_vector_type(2)));

// two adjacent texels (x0,x0+1), each (c0,c1),(c2,0) as half2 pairs; 16B
struct __align__(8) HQuad { half2v p0, p1, p2, p3; };

#if __has_builtin(__builtin_amdgcn_fdot2)
#define FDOT2(a, b, c) __builtin_amdgcn_fdot2((a), (b), (c), false)
#else
#define FDOT2(a, b, c) fmaf((float)(a).x, (float)(b).x, fmaf((float)(a).y, (float)(b).y, (c)))
#endif

#if __has_builtin(__builtin_amdgcn_exp2f)
#define EXP2F(x) __builtin_amdgcn_exp2f(x)
#else
#define EXP2F(x) exp2f(x)
#endif

// ---------- quadrant repack: rows 254..511 only; XCD-swizzled (img = blk&7) ----------
// grid = 8 * PACK_PAIRS blocks; block (b, r) packs rows 254+2r, 255+2r (1024 px, 4 px/thread)
__global__ __launch_bounds__(256) void repack_quad(
    const float* __restrict__ x,   // [B,3,H,W]
    half8v* __restrict__ xp)       // [B,H,W] half4, only rows >=254 filled
{
    int b = blockIdx.x & 7;
    int r = blockIdx.x >> 3;                       // [0, PACK_PAIRS)
    int pix = ((PACK_ROW0 + 2 * r) << 9) + threadIdx.x * 4;
    const float* xb = x + (size_t)b * 3 * PLANE;
    float4 a0 = *(const float4*)(xb + pix);
    float4 a1 = *(const float4*)(xb + PLANE + pix);
    float4 a2 = *(const float4*)(xb + 2 * PLANE + pix);
    half8v o0, o1;
    o0[0] = (_Float16)a0.x; o0[1] = (_Float16)a1.x; o0[2] = (_Float16)a2.x; o0[3] = (_Float16)0.f;
    o0[4] = (_Float16)a0.y; o0[5] = (_Float16)a1.y; o0[6] = (_Float16)a2.y; o0[7] = (_Float16)0.f;
    o1[0] = (_Float16)a0.z; o1[1] = (_Float16)a1.z; o1[2] = (_Float16)a2.z; o1[3] = (_Float16)0.f;
    o1[4] = (_Float16)a0.w; o1[5] = (_Float16)a1.w; o1[6] = (_Float16)a2.w; o1[7] = (_Float16)0.f;
    size_t base = (size_t)b * (PLANE / 2) + (size_t)(pix >> 1);
    xp[base]     = o0;
    xp[base + 1] = o1;
}

// ---------- main: 1 px/thread; scalar row bases; pk_fma conv; XCD-swizzled ----------
__global__ __launch_bounds__(256) void seesaw_v9(
    const float* __restrict__ x,     // [B,3,H,W] fp32 (conv + mirror)
    const char* __restrict__ xpack,  // [B,H,W] half4 as bytes
    const float* __restrict__ w1, const float* __restrict__ b1,
    const float* __restrict__ w2, const float* __restrict__ b2,
    float* __restrict__ out)
{
    int t = threadIdx.x;
    int b    = blockIdx.x & 7;           // image -> XCD locality
    int rest = blockIdx.x >> 3;          // [0, 1024)
    int i    = rest >> 1;                // SCALAR row (block covers half a row)
    int j    = ((rest & 1) << 8) + t;    // 0..511

    const float* xb = x + (size_t)b * 3 * PLANE;
    const char*  hb = xpack + ((size_t)b << 21);   // PLANE * 8 bytes

    // ---- gather the 27 conv inputs (flat, masked), scalar row bases ----
    float v[27];   // k = c*9 + di*3 + dj
    int cm1 = j - 1; if (cm1 < 0) cm1 = 0;
    int cp1 = j + 1; if (cp1 > 511) cp1 = 511;
    bool jlo = (j == 0), jhi = (j == 511);

    if (i >= 1 && i <= 510) {            // interior rows (uniform branch)
#pragma unroll
        for (int di = 0; di < 3; di++) {
            const float* row = xb + ((i + di - 1) << 9);
#pragma unroll
            for (int c = 0; c < 3; c++) {
                const float* rc = row + c * PLANE;
                float vm = rc[cm1]; if (jlo) vm = 0.f;
                float v0 = rc[j];
                float vp = rc[cp1]; if (jhi) vp = 0.f;
                v[c * 9 + di * 3 + 0] = vm;
                v[c * 9 + di * 3 + 1] = v0;
                v[c * 9 + di * 3 + 2] = vp;
            }
        }
    } else {                              // y-edge rows (16/8192 blocks)
#pragma unroll
        for (int di = 0; di < 3; di++) {
            int y = i + di - 1;
            bool yv = (unsigned)y < (unsigned)HDIM;
            const float* row = xb + ((yv ? y : 0) << 9);
#pragma unroll
            for (int c = 0; c < 3; c++) {
                const float* rc = row + c * PLANE;
                float vm = rc[cm1]; if (jlo || !yv) vm = 0.f;
                float v0 = rc[j];   if (!yv)        v0 = 0.f;
                float vp = rc[cp1]; if (jhi || !yv) vp = 0.f;
                v[c * 9 + di * 3 + 0] = vm;
                v[c * 9 + di * 3 + 1] = v0;
                v[c * 9 + di * 3 + 2] = vp;
            }
        }
    }

    // ---- 27-tap dot via packed f32 FMA (v_pk_fma_f32) ----
    f2v V[13];
#pragma unroll
    for (int k = 0; k < 13; k++) { V[k][0] = v[2 * k]; V[k][1] = v[2 * k + 1]; }

    float acc[8];
#pragma unroll
    for (int e = 0; e < 8; e++) {
        const float* we = w1 + e * 27;
        f2v a2; a2[0] = b1[e]; a2[1] = 0.f;
#pragma unroll
        for (int k = 0; k < 13; k++) {
            f2v ww; ww[0] = we[2 * k]; ww[1] = we[2 * k + 1];
            a2 = __builtin_elementwise_fma(V[k], ww, a2);
        }
        acc[e] = a2[0] + a2[1] + v[26] * we[26];
    }

    // ---- sigmoid via raw exp2, pre-scaled by 256 ----
    const float NLOG2E = -1.44269504f;
    float s256[8];
#pragma unroll
    for (int e = 0; e < 8; e++)
        s256[e] = 256.0f * __builtin_amdgcn_rcpf(1.0f + EXP2F(acc[e] * NLOG2E));

    // ---- w2 rows packed to half2 (wave-uniform) ----
    half2v w2a[5], w2b[5];
#pragma unroll
    for (int q = 0; q < 5; q++) {
        w2a[q][0] = (_Float16)w2[q * 3];
        w2a[q][1] = (_Float16)w2[q * 3 + 1];
        w2b[q][0] = (_Float16)w2[q * 3 + 2];
        w2b[q][1] = (_Float16)0.f;
    }

    const float k511 = 256.0f / 511.0f;
    float fxb = fmaf((float)i, k511, 255.5f);   // feeds gx (reference axis swap)
    float fyb = fmaf((float)j, k511, 255.5f);

    // ---- gather phase 1: addresses + weights for 5 points ----
    int   adr[5][2];
    float wY0[5], wY1[5], wX0[5], wX1[5];
#pragma unroll
    for (int q = 0; q < 5; q++) {
        float ixf = (q < 4) ? (fxb + s256[2 * q])     : fxb;
        float iyf = (q < 4) ? (fyb + s256[2 * q + 1]) : fyb;
        float wx1 = ixf - truncf(ixf);
        float wy1 = iyf - truncf(iyf);
        int ix0 = (int)ixf, iy0 = (int)iyf;     // positive: trunc == floor; always >= 255
        float wx0 = 1.f - wx1, wy0 = 1.f - wy1;

        float wx0v = (ix0 <= 511) ? wx0 : 0.f;
        float wx1v = (ix0 <= 510) ? wx1 : 0.f;
        float wy0v = (iy0 <= 511) ? wy0 : 0.f;
        float wy1v = (iy0 <= 510) ? wy1 : 0.f;
        int x0c = min(ix0, 511);
        int y0c = min(iy0, 511), y1c = min(iy0 + 1, 511);

        float wxs = wx0v + wx1v;
        wX0[q] = wx0v; wX1[q] = wx1v;
        wY0[q] = wy0v; wY1[q] = wy1v;
        // dead rows -> broadcast packed texel (weight is 0)
        adr[q][0] = (wy0v * wxs > 0.f) ? ((y0c << 9) + x0c) : DEAD_ADDR;
        adr[q][1] = (wy1v * wxs > 0.f) ? ((y1c << 9) + x0c) : DEAD_ADDR;
    }

    // ---- gather phase 2: all 10 pair-loads back-to-back ----
    HQuad qv[5][2];
#pragma unroll
    for (int q = 0; q < 5; q++) {
        qv[q][0] = *(const HQuad*)(hb + ((size_t)adr[q][0] << 3));
        qv[q][1] = *(const HQuad*)(hb + ((size_t)adr[q][1] << 3));
    }

    // ---- gather phase 3: fp16 dot per texel, bilinear combine ----
    float og[3] = {0.f, 0.f, 0.f};
#pragma unroll
    for (int q = 0; q < 5; q++) {
        int g = q / 3;              // 0,0,0,1,1
        float dl0 = FDOT2(qv[q][0].p0, w2a[q], FDOT2(qv[q][0].p1, w2b[q], 0.f));
        float dh0 = FDOT2(qv[q][0].p2, w2a[q], FDOT2(qv[q][0].p3, w2b[q], 0.f));
        float dl1 = FDOT2(qv[q][1].p0, w2a[q], FDOT2(qv[q][1].p1, w2b[q], 0.f));
        float dh1 = FDOT2(qv[q][1].p2, w2a[q], FDOT2(qv[q][1].p3, w2b[q], 0.f));
        float r0 = fmaf(dh0, wX1[q], dl0 * wX0[q]);
        float r1 = fmaf(dh1, wX1[q], dl1 * wX0[q]);
        og[g] = fmaf(r1, wY1[q], fmaf(r0, wY0[q], og[g]));
    }

    // ---- mirror points p=5..8: only pixel (0,0) of each image contributes ----
    if ((i | j) == 0) {
#pragma unroll
        for (int p = 5; p < 9; p++) {
            float ixf = fxb + 512.0f - s256[2 * (p - 5)];
            float iyf = fyb + 512.0f - s256[2 * (p - 5) + 1];
            float ix0f = floorf(ixf), iy0f = floorf(iyf);
            float wx1 = ixf - ix0f, wy1 = iyf - iy0f;
            float wx0 = 1.f - wx1,  wy0 = 1.f - wy1;
            int ix0 = (int)ix0f, iy0 = (int)iy0f;
            float s0 = 0.f, s1 = 0.f, s2 = 0.f;
            for (int cy = 0; cy < 2; cy++) {
                int yc2 = iy0 + cy;
                if (yc2 < 0 || yc2 >= HDIM) continue;
                float wy = cy ? wy1 : wy0;
                for (int cx = 0; cx < 2; cx++) {
                    int xcc2 = ix0 + cx;
                    if (xcc2 < 0 || xcc2 >= WDIM) continue;
                    float wgt = wy * (cx ? wx1 : wx0);
                    int base = (yc2 << 9) + xcc2;
                    s0 = fmaf(xb[base],             wgt, s0);
                    s1 = fmaf(xb[PLANE + base],     wgt, s1);
                    s2 = fmaf(xb[2 * PLANE + base], wgt, s2);
                }
            }
            int g  = p / 3;
            int k0 = (p % 3) * 3;
            og[g] = fmaf(s0, w2[g * 9 + k0 + 0], og[g]);
            og[g] = fmaf(s1, w2[g * 9 + k0 + 1], og[g]);
            og[g] = fmaf(s2, w2[g * 9 + k0 + 2], og[g]);
        }
    }

    // ---- bias + relu + store ----
    size_t ob = (size_t)(b * 3) * PLANE + ((size_t)i << 9) + j;
#pragma unroll
    for (int g = 0; g < 3; g++) {
        float vv = og[g] + b2[g];
        out[ob + (size_t)g * PLANE] = vv > 0.f ? vv : 0.f;
    }
}

// ---------- no-workspace fallback (round-1 style) ----------
__global__ __launch_bounds__(256) void seesaw_fused_v1(
    const float* __restrict__ x, const float* __restrict__ w1,
    const float* __restrict__ b1, const float* __restrict__ w2,
    const float* __restrict__ b2, float* __restrict__ out)
{
    int t = threadIdx.x;
    int gid = blockIdx.x * 256 + t;
    int j = gid & (WDIM - 1);
    int i = (gid >> 9) & (HDIM - 1);
    int b = gid >> 18;
    const float* xb = x + (size_t)b * 3 * PLANE;
    float acc[8];
#pragma unroll
    for (int e = 0; e < 8; e++) acc[e] = b1[e];
#pragma unroll
    for (int di = 0; di < 3; di++) {
        int y = i + di - 1;
        if (y < 0 || y >= HDIM) continue;
#pragma unroll
        for (int dj = 0; dj < 3; dj++) {
            int xc = j + dj - 1;
            if (xc < 0 || xc >= WDIM) continue;
            size_t base = (size_t)y * WDIM + xc;
#pragma unroll
            for (int c = 0; c < 3; c++) {
                float v = xb[(size_t)c * PLANE + base];
#pragma unroll
                for (int e = 0; e < 8; e++)
                    acc[e] = fmaf(v, w1[e * 27 + c * 9 + di * 3 + dj], acc[e]);
            }
        }
    }
    float s[8];
#pragma unroll
    for (int e = 0; e < 8; e++) s[e] = 1.0f / (1.0f + __expf(-acc[e]));
    const float inv511 = 1.0f / 511.0f;
    float bx = (float)i * inv511, by = (float)j * inv511;
    float og0 = 0.f, og1 = 0.f, og2 = 0.f;
#pragma unroll
    for (int p = 0; p < 9; p++) {
        float c0, c1;
        if (p < 4)       { c0 = s[2 * p];              c1 = s[2 * p + 1]; }
        else if (p == 4) { c0 = 0.f;                   c1 = 0.f; }
        else             { c0 = 2.0f - s[2 * (p - 5)]; c1 = 2.0f - s[2 * (p - 5) + 1]; }
        float ixf = (bx + c0) * 256.0f + 255.5f;
        float iyf = (by + c1) * 256.0f + 255.5f;
        float ix0f = floorf(ixf), iy0f = floorf(iyf);
        float wx1 = ixf - ix0f, wy1 = iyf - iy0f;
        float wx0 = 1.f - wx1,  wy0 = 1.f - wy1;
        int ix0 = (int)ix0f, iy0 = (int)iy0f;
        float s0 = 0.f, s1 = 0.f, s2 = 0.f;
#pragma unroll
        for (int cy = 0; cy < 2; cy++) {
            int yc = iy0 + cy;
            if (yc < 0 || yc >= HDIM) continue;
            float wy = cy ? wy1 : wy0;
#pragma unroll
            for (int cx = 0; cx < 2; cx++) {
                int xcc = ix0 + cx;
                if (xcc < 0 || xcc >= WDIM) continue;
                float wgt = wy * (cx ? wx1 : wx0);
                size_t base = (size_t)yc * WDIM + xcc;
                s0 = fmaf(xb[base],             wgt, s0);
                s1 = fmaf(xb[PLANE + base],     wgt, s1);
                s2 = fmaf(xb[2 * PLANE + base], wgt, s2);
            }
        }
        int g  = p / 3;
        int k0 = (p % 3) * 3;
        float* og = (g == 0) ? &og0 : (g == 1) ? &og1 : &og2;
        *og = fmaf(s0, w2[g * 9 + k0 + 0], *og);
        *og = fmaf(s1, w2[g * 9 + k0 + 1], *og);
        *og = fmaf(s2, w2[g * 9 + k0 + 2], *og);
    }
    size_t ob = (size_t)(b * 3) * PLANE + (size_t)i * WDIM + j;
    float v0 = og0 + b2[0], v1 = og1 + b2[1], v2 = og2 + b2[2];
    out[ob]             = v0 > 0.f ? v0 : 0.f;
    out[ob + PLANE]     = v1 > 0.f ? v1 : 0.f;
    out[ob + 2 * PLANE] = v2 > 0.f ? v2 : 0.f;
}

extern "C" void kernel_launch(void* const* d_in, const int* in_sizes, int n_in,
                              void* d_out, int out_size, void* d_ws, size_t ws_size,
                              hipStream_t stream) {
    const float* x  = (const float*)d_in[0];
    const float* w1 = (const float*)d_in[1];
    const float* b1 = (const float*)d_in[2];
    const float* w2 = (const float*)d_in[3];
    const float* b2 = (const float*)d_in[4];
    float* out = (float*)d_out;

    int total = BATCH * HDIM * WDIM;                 // 2,097,152
    size_t need = (size_t)total * 8 + 16;            // 16 MiB fp16x4 pack + pad

    if (ws_size >= need) {
        repack_quad<<<8 * PACK_PAIRS, 256, 0, stream>>>(x, (half8v*)d_ws);
        seesaw_v9<<<total / 256, 256, 0, stream>>>(x, (const char*)d_ws,
                                                   w1, b1, w2, b2, out);
    } else {
        seesaw_fused_v1<<<total / 256, 256, 0, stream>>>(x, w1, b1, w2, b2, out);
    }
}